// Round 12
// baseline (320.731 us; speedup 1.0000x reference)
//
#include <hip/hip_runtime.h>
#include <stdint.h>

#define BATCH 524288
#define OBSD  64

typedef short v8s __attribute__((ext_vector_type(8)));
typedef float v4f __attribute__((ext_vector_type(4)));

union U8 { int4 i4; v8s v; uint32_t u[4]; };

// gfx950 packed fp32->bf16 convert (RNE)
__device__ __forceinline__ uint32_t pk2(float a, float b) {
  uint32_t r;
  asm("v_cvt_pk_bf16_f32 %0, %1, %2" : "=v"(r) : "v"(a), "v"(b));
  return r;
}

// async global->LDS, 16 B per lane (width=16). LDS dst is wave-uniform base;
// HW scatters lane i to dst + i*16.
__device__ __forceinline__ void glds16(const uint16_t* g, uint16_t* l) {
  __builtin_amdgcn_global_load_lds(
      (const __attribute__((address_space(1))) uint32_t*)g,
      (__attribute__((address_space(3))) uint32_t*)l, 16, 0, 0);
}

// ---- prep: weights -> bf16 frag-order image (W3p negated) ---- (UNCHANGED)
// Wall (uint16_t elems), all frag-order (frag = 512 elems, lane-major):
//   W1t@0      frag(rt,ks2): (rt*2+ks)*512 + lane*8      [8192]
//   W1p@8192   same                                       [8192]
//   W2t@16384  frag(rt,ks4): (rt*4+ks)*512 + lane*8      [16384]
//   W2p@32768                                             [16384]
//   W3t@49152                                             [16384]
//   W3n@65536  (pre-negated pW3)                          [16384]
__global__ void rnd_prep(const float* __restrict__ tW1, const float* __restrict__ tW2,
                         const float* __restrict__ tW3, const float* __restrict__ pW1,
                         const float* __restrict__ pW2, const float* __restrict__ pW3,
                         uint16_t* __restrict__ Wall, float* __restrict__ sums) {
  int g = blockIdx.x * 256 + threadIdx.x;   // 40*256 = 10240 units x 8 elems
  if (g < 2) sums[g] = 0.0f;
  const float* src;
  uint16_t* dst;
  float sgn = 1.f;
  if (g < 2048) {                            // W1 frags (verified R7 pattern)
    int u = g;
    int m = u >> 10; u &= 1023;
    int rt = u >> 7, ks = (u >> 6) & 1, lane = u & 63;
    int n = lane & 15, qq = lane >> 4;
    src = (m ? pW1 : tW1) + (rt * 16 + n) * 64 + ks * 32 + qq * 8;
    dst = Wall + m * 8192 + u * 8;
  } else if (g < 6144) {                     // W2 frags (same 128x128 pattern)
    int u = g - 2048;
    int m = u >> 11; u &= 2047;
    int rt = u >> 8, ks = (u >> 6) & 3, lane = u & 63;
    int n = lane & 15, qq = lane >> 4;
    src = (m ? pW2 : tW2) + (rt * 16 + n) * 128 + ks * 32 + qq * 8;
    dst = Wall + 16384 + m * 16384 + u * 8;
  } else {                                   // W3 frags (predictor negated)
    int u = g - 6144;
    int m = u >> 11; u &= 2047;
    int rt = u >> 8, ks = (u >> 6) & 3, lane = u & 63;
    int n = lane & 15, qq = lane >> 4;
    src = (m ? pW3 : tW3) + (rt * 16 + n) * 128 + ks * 32 + qq * 8;
    sgn = m ? -1.f : 1.f;
    dst = Wall + 49152 + m * 16384 + u * 8;
  }
  float4 f0 = *(const float4*)src, f1 = *(const float4*)(src + 4);
  U8 u8;
  u8.u[0] = pk2(sgn * f0.x, sgn * f0.y); u8.u[1] = pk2(sgn * f0.z, sgn * f0.w);
  u8.u[2] = pk2(sgn * f1.x, sgn * f1.y); u8.u[3] = pk2(sgn * f1.z, sgn * f1.w);
  *(int4*)dst = u8.i4;
}

// ---- main (R19 = exact R4-measured kernel, launch_bounds 2 -> 3):
// R4 measured: main 114.2us, MfmaUtil 31%, VALU-only ~4%, 0 conflicts,
// VGPR=128 -> NOT register-bound; Occupancy 19.7% (2 blocks/CU = 2 waves/SIMD)
// was declared, not forced. R11 (barrier-free) regressed -> stall is latency
// that 2 waves/SIMD cannot hide, not barrier lockstep. This build: 3 blocks/CU
// (LDS 51712*3 = 155136 <= 163840; VGPR 128 <= 168 cap) -> 3 waves/SIMD,
// cross-block phase diversity hides barrier drains. Codegen otherwise
// identical to the verified kernel. Chunk stream (ck -> buf k%3):
//   c0 W1t, c1 W2t.lo, c2 W2t.hi, c3 W1p, c4 W2p.lo, c5 W2p.hi,
//   c6 W3t.lo, c7 W3n.lo, c8 W3t.hi, c9 W3n.hi. ----
__global__ __launch_bounds__(256, 3) void rnd_main(
    const float* __restrict__ obs, const uint16_t* __restrict__ Wall,
    const float* __restrict__ b1t, const float* __restrict__ b2t,
    const float* __restrict__ b1p, const float* __restrict__ b2p,
    const float* __restrict__ b3t, const float* __restrict__ b3p,
    float* __restrict__ rewards, float* __restrict__ sums) {
  extern __shared__ __align__(16) uint16_t Wl[];  // 49152 B ring + 2560 B bias
  const int t    = threadIdx.x;
  const int lane = t & 63;
  const int wv   = t >> 6;
  const int n    = lane & 15;
  const int q    = lane >> 4;
  const int s0   = (blockIdx.x * 4 + wv) * 64;

  const uint16_t* gsrc = Wall + wv * 2048 + lane * 8;   // per-chunk: + off + j*512
  uint16_t*       lbas = Wl + wv * 2048;                // elems; + bufoff/2 + j*512
  auto stage = [&](int chunkElemOff, int bufByteOff) {
    #pragma unroll
    for (int j = 0; j < 4; ++j)
      glds16(gsrc + chunkElemOff + j * 512, lbas + bufByteOff / 2 + j * 512);
  };

  const uint16_t* rb = Wl + lane * 8;      // frag read base; +bufoff/2 + frag*512
  float* Bl = (float*)(Wl + 24576);        // bias stash @byte 49152, 640 floats
  // Bl: [0]=b1t [128]=b2t [256]=b1p [384]=b2p [512]=b3t-b3p

  // ---- kick off first three chunks + bias stash + obs loads ----
  stage(0, 0);            // c0 W1t    -> b0
  stage(16384, 16384);    // c1 W2t.lo -> b1
  stage(24576, 32768);    // c2 W2t.hi -> b2
  {
    int i = t;
    #pragma unroll
    for (int it = 0; it < 3; ++it, i += 256)
      if (i < 640) {
        int seg = i >> 7, off = i & 127;
        float v;
        if (seg == 0) v = b1t[off];
        else if (seg == 1) v = b2t[off];
        else if (seg == 2) v = b1p[off];
        else if (seg == 3) v = b2p[off];
        else v = b3t[off] - b3p[off];
        Bl[i] = v;
      }
  }
  float4 of[16];
  #pragma unroll
  for (int ct = 0; ct < 4; ++ct)
    #pragma unroll
    for (int ks = 0; ks < 2; ++ks) {
      const float* p = obs + (size_t)(s0 + ct * 16 + n) * OBSD + ks * 32 + q * 8;
      of[(ct * 2 + ks) * 2 + 0] = *(const float4*)p;
      of[(ct * 2 + ks) * 2 + 1] = *(const float4*)(p + 4);
    }
  v8s obf[4][2];
  #pragma unroll
  for (int ct = 0; ct < 4; ++ct)
    #pragma unroll
    for (int ks = 0; ks < 2; ++ks) {
      float4 f0 = of[(ct * 2 + ks) * 2 + 0];
      float4 f1 = of[(ct * 2 + ks) * 2 + 1];
      U8 u;
      u.u[0] = pk2(f0.x, f0.y); u.u[1] = pk2(f0.z, f0.w);
      u.u[2] = pk2(f1.x, f1.y); u.u[3] = pk2(f1.z, f1.w);
      obf[ct][ks] = u.v;
    }

  // bias init for 4 row-tiles (rtBase..rtBase+3) from LDS stash
  auto bias4 = [&](int bbase, int rtBase, v4f (&a)[4][4]) {
    #pragma unroll
    for (int r = 0; r < 4; ++r) {
      v4f c = *(const v4f*)(Bl + bbase + (rtBase + r) * 16 + q * 4);
      #pragma unroll
      for (int ct = 0; ct < 4; ++ct) a[r][ct] = c;
    }
  };
  // ReLU + pack + permlane into B-frag order; rows r0..3 -> BF[ksBase..ksBase+1]
  auto pack4 = [&](v4f (&a)[4][4], v8s (&BF)[4][4], int ksBase) {
    uint32_t P[4][4][2];
    #pragma unroll
    for (int r = 0; r < 4; ++r)
      #pragma unroll
      for (int ct = 0; ct < 4; ++ct) {
        v4f v = a[r][ct];
        v[0] = fmaxf(v[0], 0.f); v[1] = fmaxf(v[1], 0.f);
        v[2] = fmaxf(v[2], 0.f); v[3] = fmaxf(v[3], 0.f);
        P[r][ct][0] = pk2(v[0], v[1]);
        P[r][ct][1] = pk2(v[2], v[3]);
      }
    #pragma unroll
    for (int kk = 0; kk < 2; ++kk)
      #pragma unroll
      for (int ct = 0; ct < 4; ++ct) {
        uint32_t x0 = P[2 * kk][ct][0],     x1 = P[2 * kk][ct][1];
        uint32_t y0 = P[2 * kk + 1][ct][0], y1 = P[2 * kk + 1][ct][1];
        asm("v_permlane32_swap_b32 %0, %1" : "+v"(x0), "+v"(y0));
        asm("v_permlane16_swap_b32 %0, %1" : "+v"(x0), "+v"(y0));
        asm("v_permlane32_swap_b32 %0, %1" : "+v"(x1), "+v"(y1));
        asm("v_permlane16_swap_b32 %0, %1" : "+v"(x1), "+v"(y1));
        U8 u; u.u[0] = x0; u.u[1] = x1; u.u[2] = y0; u.u[3] = y1;
        BF[ksBase + kk][ct] = u.v;
      }
  };
  // layer 1 (full 16KB chunk at ring offset 0), two 4-row halves
  auto layer1 = [&](int bbase, v8s (&BF)[4][4]) {
    v4f a[4][4];
    bias4(bbase, 0, a);
    __builtin_amdgcn_s_setprio(1);
    #pragma unroll
    for (int ks = 0; ks < 2; ++ks)
      #pragma unroll
      for (int r = 0; r < 4; ++r) {
        U8 u; u.i4 = *(const int4*)(rb + (r * 2 + ks) * 512);
        #pragma unroll
        for (int ct = 0; ct < 4; ++ct)
          a[r][ct] = __builtin_amdgcn_mfma_f32_16x16x32_bf16(u.v, obf[ct][ks], a[r][ct], 0, 0, 0);
      }
    __builtin_amdgcn_s_setprio(0);
    pack4(a, BF, 0);
    bias4(bbase, 4, a);
    __builtin_amdgcn_s_setprio(1);
    #pragma unroll
    for (int ks = 0; ks < 2; ++ks)
      #pragma unroll
      for (int r = 0; r < 4; ++r) {
        U8 u; u.i4 = *(const int4*)(rb + ((r + 4) * 2 + ks) * 512);
        #pragma unroll
        for (int ct = 0; ct < 4; ++ct)
          a[r][ct] = __builtin_amdgcn_mfma_f32_16x16x32_bf16(u.v, obf[ct][ks], a[r][ct], 0, 0, 0);
      }
    __builtin_amdgcn_s_setprio(0);
    pack4(a, BF, 2);
  };
  // one 16KB half-layer chunk (4 row-tiles, full K=128), accumulate into a
  auto halfmm = [&](int bufOff, v8s (&BFin)[4][4], v4f (&a)[4][4]) {
    __builtin_amdgcn_s_setprio(1);
    #pragma unroll
    for (int ks = 0; ks < 4; ++ks)
      #pragma unroll
      for (int r = 0; r < 4; ++r) {
        U8 u; u.i4 = *(const int4*)(rb + bufOff / 2 + (r * 4 + ks) * 512);
        #pragma unroll
        for (int ct = 0; ct < 4; ++ct)
          a[r][ct] = __builtin_amdgcn_mfma_f32_16x16x32_bf16(u.v, BFin[ks][ct], a[r][ct], 0, 0, 0);
      }
    __builtin_amdgcn_s_setprio(0);
  };

  v8s BF1[4][4], BF2t[4][4], BF2p[4][4];

  __syncthreads();                               // c0..c2 + biases ready
  layer1(0, BF1);                                // ph0 (b0=W1t)
  __syncthreads(); stage(8192, 0);               // c3 W1p -> b0
  { v4f a[4][4]; bias4(128, 0, a); halfmm(16384, BF1, a); pack4(a, BF2t, 0); }  // ph1 (b1=W2t.lo)
  __syncthreads(); stage(32768, 16384);          // c4 W2p.lo -> b1
  { v4f a[4][4]; bias4(128, 4, a); halfmm(32768, BF1, a); pack4(a, BF2t, 2); }  // ph2 (b2=W2t.hi)
  __syncthreads(); stage(40960, 32768);          // c5 W2p.hi -> b2
  layer1(256, BF1);                              // ph3 (b0=W1p)
  __syncthreads(); stage(49152, 0);              // c6 W3t.lo -> b0
  { v4f a[4][4]; bias4(384, 0, a); halfmm(16384, BF1, a); pack4(a, BF2p, 0); }  // ph4 (b1=W2p.lo)
  __syncthreads(); stage(65536, 16384);          // c7 W3n.lo -> b1
  { v4f a[4][4]; bias4(384, 4, a); halfmm(32768, BF1, a); pack4(a, BF2p, 2); }  // ph5 (b2=W2p.hi)
  __syncthreads(); stage(57344, 32768);          // c8 W3t.hi -> b2

  // ---- layer 3, rows 0..63 (lo) then 64..127 (hi); reduce each then free ----
  float p[4] = {0.f, 0.f, 0.f, 0.f};
  {
    v4f a[4][4];
    #pragma unroll
    for (int r = 0; r < 4; ++r) {
      v4f c = *(const v4f*)(Bl + 512 + r * 16 + q * 4);
      #pragma unroll
      for (int ct = 0; ct < 4; ++ct) a[r][ct] = c;
    }
    halfmm(0, BF2t, a);                          // ph6 (b0=W3t.lo)
    __syncthreads(); stage(73728, 0);            // c9 W3n.hi -> b0
    halfmm(16384, BF2p, a);                      // ph7 (b1=W3n.lo)
    #pragma unroll
    for (int r = 0; r < 4; ++r)
      #pragma unroll
      for (int ct = 0; ct < 4; ++ct) {
        v4f v = a[r][ct];
        p[ct] += v[0]*v[0] + v[1]*v[1] + v[2]*v[2] + v[3]*v[3];
      }
  }
  __syncthreads();                               // c9 resident (vmcnt drained)
  {
    v4f a[4][4];
    #pragma unroll
    for (int r = 0; r < 4; ++r) {
      v4f c = *(const v4f*)(Bl + 512 + (r + 4) * 16 + q * 4);
      #pragma unroll
      for (int ct = 0; ct < 4; ++ct) a[r][ct] = c;
    }
    halfmm(32768, BF2t, a);                      // ph8 (b2=W3t.hi)
    halfmm(0, BF2p, a);                          // ph9 (b0=W3n.hi)
    #pragma unroll
    for (int r = 0; r < 4; ++r)
      #pragma unroll
      for (int ct = 0; ct < 4; ++ct) {
        v4f v = a[r][ct];
        p[ct] += v[0]*v[0] + v[1]*v[1] + v[2]*v[2] + v[3]*v[3];
      }
  }

  // ---- epilogue: reward = mean over 128 out-dims of diff^2 ----
  float r[4];
  #pragma unroll
  for (int ct = 0; ct < 4; ++ct) {
    p[ct] += __shfl_xor(p[ct], 32);
    p[ct] += __shfl_xor(p[ct], 16);
    r[ct] = p[ct] * (1.0f / 128.0f);
  }
  if (q == 0) {
    #pragma unroll
    for (int ct = 0; ct < 4; ++ct) rewards[s0 + ct * 16 + n] = r[ct];
  }
  float s  = r[0] + r[1] + r[2] + r[3];
  float ss = r[0]*r[0] + r[1]*r[1] + r[2]*r[2] + r[3]*r[3];
  s  += __shfl_xor(s, 8);  s  += __shfl_xor(s, 4);  s  += __shfl_xor(s, 2);  s  += __shfl_xor(s, 1);
  ss += __shfl_xor(ss, 8); ss += __shfl_xor(ss, 4); ss += __shfl_xor(ss, 2); ss += __shfl_xor(ss, 1);
  __syncthreads();                  // all reads of Wl ring done; reuse as scratch
  float* red = (float*)Wl;
  if (lane == 0) { red[wv] = s; red[8 + wv] = ss; }
  __syncthreads();
  if (t == 0) {
    atomicAdd(&sums[0], red[0] + red[1] + red[2] + red[3]);
    atomicAdd(&sums[1], red[8] + red[9] + red[10] + red[11]);
  }
}

// ---- normalize: Chan-merge with running stats ---- (UNCHANGED)
__global__ void rnd_norm(const float* __restrict__ rewards, const float* __restrict__ sums,
                         const float* __restrict__ rm, const float* __restrict__ rm2,
                         const float* __restrict__ rc, float* __restrict__ out) {
  float S = sums[0], SS = sums[1];
  float nb = (float)BATCH;
  float bm = S / nb;
  float bm2 = SS - nb * bm * bm;
  float cnt = rc[0];
  float newc = cnt + nb;
  float delta = bm - rm[0];
  float newmean = rm[0] + delta * nb / newc;
  float newm2 = rm2[0] + bm2 + delta * delta * cnt * nb / newc;
  float sd = (newc > 1.f) ? sqrtf(newm2 / (newc - 1.f)) : 1.f;
  float inv = 1.f / (sd + 1e-8f);
  int i = (blockIdx.x * 256 + threadIdx.x) * 4;
  float4 r = *(const float4*)(rewards + i);
  float4 o;
  o.x = (r.x - newmean) * inv; o.y = (r.y - newmean) * inv;
  o.z = (r.z - newmean) * inv; o.w = (r.w - newmean) * inv;
  *(float4*)(out + i) = o;
}

extern "C" void kernel_launch(void* const* d_in, const int* in_sizes, int n_in,
                              void* d_out, int out_size, void* d_ws, size_t ws_size,
                              hipStream_t stream) {
  const float* obs = (const float*)d_in[0];
  const float* rm  = (const float*)d_in[1];
  const float* rm2 = (const float*)d_in[2];
  const float* rc  = (const float*)d_in[3];
  const float* tW1 = (const float*)d_in[4];
  const float* tb1 = (const float*)d_in[5];
  const float* tW2 = (const float*)d_in[6];
  const float* tb2 = (const float*)d_in[7];
  const float* tW3 = (const float*)d_in[8];
  const float* tb3 = (const float*)d_in[9];
  const float* pW1 = (const float*)d_in[10];
  const float* pb1 = (const float*)d_in[11];
  const float* pW2 = (const float*)d_in[12];
  const float* pb2 = (const float*)d_in[13];
  const float* pW3 = (const float*)d_in[14];
  const float* pb3 = (const float*)d_in[15];

  float*    sums    = (float*)d_ws;
  float*    rewards = (float*)((char*)d_ws + 256);
  uint16_t* Wall    = (uint16_t*)((char*)d_ws + 256 + (size_t)BATCH * 4);

  (void)hipFuncSetAttribute((const void*)rnd_main,
                            hipFuncAttributeMaxDynamicSharedMemorySize, 51712);

  rnd_prep<<<40, 256, 0, stream>>>(tW1, tW2, tW3, pW1, pW2, pW3, Wall, sums);
  rnd_main<<<BATCH / 256, 256, 51712, stream>>>(obs, Wall, tb1, tb2, pb1, pb2,
                                                tb3, pb3, rewards, sums);
  rnd_norm<<<BATCH / 1024, 256, 0, stream>>>(rewards, sums, rm, rm2, rc, (float*)d_out);
}

// Round 14
// 269.808 us; speedup vs baseline: 1.1887x; 1.1887x over previous
//
#include <hip/hip_runtime.h>
#include <stdint.h>

#define BATCH 524288
#define OBSD  64

typedef short v8s __attribute__((ext_vector_type(8)));
typedef float v4f __attribute__((ext_vector_type(4)));

union U8 { int4 i4; v8s v; uint32_t u[4]; };

// gfx950 packed fp32->bf16 convert (RNE)
__device__ __forceinline__ uint32_t pk2(float a, float b) {
  uint32_t r;
  asm("v_cvt_pk_bf16_f32 %0, %1, %2" : "=v"(r) : "v"(a), "v"(b));
  return r;
}

// async global->LDS, 16 B per lane (width=16). LDS dst is wave-uniform base;
// HW scatters lane i to dst + i*16.
__device__ __forceinline__ void glds16(const uint16_t* g, uint16_t* l) {
  __builtin_amdgcn_global_load_lds(
      (const __attribute__((address_space(1))) uint32_t*)g,
      (__attribute__((address_space(3))) uint32_t*)l, 16, 0, 0);
}

// ---- prep: weights -> bf16 frag-order image (W3p negated) ---- (UNCHANGED)
// Wall (uint16_t elems), all frag-order (frag = 512 elems, lane-major):
//   W1t@0      frag(rt,ks2): (rt*2+ks)*512 + lane*8      [8192]
//   W1p@8192   same                                       [8192]
//   W2t@16384  frag(rt,ks4): (rt*4+ks)*512 + lane*8      [16384]
//   W2p@32768                                             [16384]
//   W3t@49152                                             [16384]
//   W3n@65536  (pre-negated pW3)                          [16384]
__global__ void rnd_prep(const float* __restrict__ tW1, const float* __restrict__ tW2,
                         const float* __restrict__ tW3, const float* __restrict__ pW1,
                         const float* __restrict__ pW2, const float* __restrict__ pW3,
                         uint16_t* __restrict__ Wall, float* __restrict__ sums) {
  int g = blockIdx.x * 256 + threadIdx.x;   // 40*256 = 10240 units x 8 elems
  if (g < 2) sums[g] = 0.0f;
  const float* src;
  uint16_t* dst;
  float sgn = 1.f;
  if (g < 2048) {                            // W1 frags (verified R7 pattern)
    int u = g;
    int m = u >> 10; u &= 1023;
    int rt = u >> 7, ks = (u >> 6) & 1, lane = u & 63;
    int n = lane & 15, qq = lane >> 4;
    src = (m ? pW1 : tW1) + (rt * 16 + n) * 64 + ks * 32 + qq * 8;
    dst = Wall + m * 8192 + u * 8;
  } else if (g < 6144) {                     // W2 frags (same 128x128 pattern)
    int u = g - 2048;
    int m = u >> 11; u &= 2047;
    int rt = u >> 8, ks = (u >> 6) & 3, lane = u & 63;
    int n = lane & 15, qq = lane >> 4;
    src = (m ? pW2 : tW2) + (rt * 16 + n) * 128 + ks * 32 + qq * 8;
    dst = Wall + 16384 + m * 16384 + u * 8;
  } else {                                   // W3 frags (predictor negated)
    int u = g - 6144;
    int m = u >> 11; u &= 2047;
    int rt = u >> 8, ks = (u >> 6) & 3, lane = u & 63;
    int n = lane & 15, qq = lane >> 4;
    src = (m ? pW3 : tW3) + (rt * 16 + n) * 128 + ks * 32 + qq * 8;
    sgn = m ? -1.f : 1.f;
    dst = Wall + 49152 + m * 16384 + u * 8;
  }
  float4 f0 = *(const float4*)src, f1 = *(const float4*)(src + 4);
  U8 u8;
  u8.u[0] = pk2(sgn * f0.x, sgn * f0.y); u8.u[1] = pk2(sgn * f0.z, sgn * f0.w);
  u8.u[2] = pk2(sgn * f1.x, sgn * f1.y); u8.u[3] = pk2(sgn * f1.z, sgn * f1.w);
  *(int4*)dst = u8.i4;
}

// ---- main (R21 = R20 resubmit, audited): R4 structure + 4-buffer ring /
// 5 barriers + pack4 sink. R4 measured: main 114.2us, MfmaUtil 31%. R12
// showed 3-blocks/CU spills (unified VGPR+AGPR), so 2 blocks/CU stands;
// attack barrier count + pack4 serialization instead.
// 4x16KB buffers b0..b3 (ck -> b(k%4)), TWO chunks consumed per barrier:
//   pair0{ph0 c0,ph1 c1} B1 stage{c4,c5}
//   pair1{ph2 c2,ph3 c3} B2 stage{c6,c7}
//   pair2{ph4 c4,ph5 c5} B3 stage{c8,c9}
//   pair3{ph6 c6,ph7 c7} B4
//   pair4{ph8 c8,ph9 c9}
// 5 barriers (was 10); prefetch distance 2 phases. pack4 of a2 results sunk
// past the following barrier into the next phase's ds_read latency window
// (register-only; input a2 not overwritten until the next bias4).
// Chunks: c0 W1t, c1 W2t.lo, c2 W2t.hi, c3 W1p, c4 W2p.lo, c5 W2p.hi,
//   c6 W3t.lo, c7 W3n.lo, c8 W3t.hi, c9 W3n.hi. ----
__global__ __launch_bounds__(256, 2) void rnd_main(
    const float* __restrict__ obs, const uint16_t* __restrict__ Wall,
    const float* __restrict__ b1t, const float* __restrict__ b2t,
    const float* __restrict__ b1p, const float* __restrict__ b2p,
    const float* __restrict__ b3t, const float* __restrict__ b3p,
    float* __restrict__ rewards, float* __restrict__ sums) {
  extern __shared__ __align__(16) uint16_t Wl[];  // 4x16KB ring + 2560B bias = 68096B
  const int t    = threadIdx.x;
  const int lane = t & 63;
  const int wv   = t >> 6;
  const int n    = lane & 15;
  const int q    = lane >> 4;
  const int s0   = (blockIdx.x * 4 + wv) * 64;

  const uint16_t* gsrc = Wall + wv * 2048 + lane * 8;   // per-chunk: + off + j*512
  uint16_t*       lbas = Wl + wv * 2048;                // elems; + bufoff/2 + j*512
  auto stage = [&](int chunkElemOff, int bufByteOff) {
    #pragma unroll
    for (int j = 0; j < 4; ++j)
      glds16(gsrc + chunkElemOff + j * 512, lbas + bufByteOff / 2 + j * 512);
  };

  const uint16_t* rb = Wl + lane * 8;      // frag read base; +bufoff/2 + frag*512
  float* Bl = (float*)(Wl + 32768);        // bias stash @byte 65536, 640 floats
  // Bl: [0]=b1t [128]=b2t [256]=b1p [384]=b2p [512]=b3t-b3p

  // ---- kick off first FOUR chunks + bias stash + obs loads ----
  stage(0, 0);            // c0 W1t    -> b0
  stage(16384, 16384);    // c1 W2t.lo -> b1
  stage(24576, 32768);    // c2 W2t.hi -> b2
  stage(8192, 49152);     // c3 W1p    -> b3
  {
    int i = t;
    #pragma unroll
    for (int it = 0; it < 3; ++it, i += 256)
      if (i < 640) {
        int seg = i >> 7, off = i & 127;
        float v;
        if (seg == 0) v = b1t[off];
        else if (seg == 1) v = b2t[off];
        else if (seg == 2) v = b1p[off];
        else if (seg == 3) v = b2p[off];
        else v = b3t[off] - b3p[off];
        Bl[i] = v;
      }
  }
  float4 of[16];
  #pragma unroll
  for (int ct = 0; ct < 4; ++ct)
    #pragma unroll
    for (int ks = 0; ks < 2; ++ks) {
      const float* p = obs + (size_t)(s0 + ct * 16 + n) * OBSD + ks * 32 + q * 8;
      of[(ct * 2 + ks) * 2 + 0] = *(const float4*)p;
      of[(ct * 2 + ks) * 2 + 1] = *(const float4*)(p + 4);
    }
  v8s obf[4][2];
  #pragma unroll
  for (int ct = 0; ct < 4; ++ct)
    #pragma unroll
    for (int ks = 0; ks < 2; ++ks) {
      float4 f0 = of[(ct * 2 + ks) * 2 + 0];
      float4 f1 = of[(ct * 2 + ks) * 2 + 1];
      U8 u;
      u.u[0] = pk2(f0.x, f0.y); u.u[1] = pk2(f0.z, f0.w);
      u.u[2] = pk2(f1.x, f1.y); u.u[3] = pk2(f1.z, f1.w);
      obf[ct][ks] = u.v;
    }

  // bias init for 4 row-tiles (rtBase..rtBase+3) from LDS stash
  auto bias4 = [&](int bbase, int rtBase, v4f (&a)[4][4]) {
    #pragma unroll
    for (int r = 0; r < 4; ++r) {
      v4f c = *(const v4f*)(Bl + bbase + (rtBase + r) * 16 + q * 4);
      #pragma unroll
      for (int ct = 0; ct < 4; ++ct) a[r][ct] = c;
    }
  };
  // ReLU + pack + permlane into B-frag order; rows r0..3 -> BF[ksBase..ksBase+1]
  auto pack4 = [&](v4f (&a)[4][4], v8s (&BF)[4][4], int ksBase) {
    uint32_t P[4][4][2];
    #pragma unroll
    for (int r = 0; r < 4; ++r)
      #pragma unroll
      for (int ct = 0; ct < 4; ++ct) {
        v4f v = a[r][ct];
        v[0] = fmaxf(v[0], 0.f); v[1] = fmaxf(v[1], 0.f);
        v[2] = fmaxf(v[2], 0.f); v[3] = fmaxf(v[3], 0.f);
        P[r][ct][0] = pk2(v[0], v[1]);
        P[r][ct][1] = pk2(v[2], v[3]);
      }
    #pragma unroll
    for (int kk = 0; kk < 2; ++kk)
      #pragma unroll
      for (int ct = 0; ct < 4; ++ct) {
        uint32_t x0 = P[2 * kk][ct][0],     x1 = P[2 * kk][ct][1];
        uint32_t y0 = P[2 * kk + 1][ct][0], y1 = P[2 * kk + 1][ct][1];
        asm("v_permlane32_swap_b32 %0, %1" : "+v"(x0), "+v"(y0));
        asm("v_permlane16_swap_b32 %0, %1" : "+v"(x0), "+v"(y0));
        asm("v_permlane32_swap_b32 %0, %1" : "+v"(x1), "+v"(y1));
        asm("v_permlane16_swap_b32 %0, %1" : "+v"(x1), "+v"(y1));
        U8 u; u.u[0] = x0; u.u[1] = x1; u.u[2] = y0; u.u[3] = y1;
        BF[ksBase + kk][ct] = u.v;
      }
  };
  // layer 1 (full 16KB chunk at ring byte offset bufOff), two 4-row halves
  auto layer1 = [&](int bufOff, int bbase, v8s (&BF)[4][4]) {
    v4f a[4][4];
    bias4(bbase, 0, a);
    __builtin_amdgcn_s_setprio(1);
    #pragma unroll
    for (int ks = 0; ks < 2; ++ks)
      #pragma unroll
      for (int r = 0; r < 4; ++r) {
        U8 u; u.i4 = *(const int4*)(rb + bufOff / 2 + (r * 2 + ks) * 512);
        #pragma unroll
        for (int ct = 0; ct < 4; ++ct)
          a[r][ct] = __builtin_amdgcn_mfma_f32_16x16x32_bf16(u.v, obf[ct][ks], a[r][ct], 0, 0, 0);
      }
    __builtin_amdgcn_s_setprio(0);
    pack4(a, BF, 0);
    bias4(bbase, 4, a);
    __builtin_amdgcn_s_setprio(1);
    #pragma unroll
    for (int ks = 0; ks < 2; ++ks)
      #pragma unroll
      for (int r = 0; r < 4; ++r) {
        U8 u; u.i4 = *(const int4*)(rb + bufOff / 2 + ((r + 4) * 2 + ks) * 512);
        #pragma unroll
        for (int ct = 0; ct < 4; ++ct)
          a[r][ct] = __builtin_amdgcn_mfma_f32_16x16x32_bf16(u.v, obf[ct][ks], a[r][ct], 0, 0, 0);
      }
    __builtin_amdgcn_s_setprio(0);
    pack4(a, BF, 2);
  };
  // one 16KB half-layer chunk (4 row-tiles, full K=128), accumulate into a
  auto halfmm = [&](int bufOff, v8s (&BFin)[4][4], v4f (&a)[4][4]) {
    __builtin_amdgcn_s_setprio(1);
    #pragma unroll
    for (int ks = 0; ks < 4; ++ks)
      #pragma unroll
      for (int r = 0; r < 4; ++r) {
        U8 u; u.i4 = *(const int4*)(rb + bufOff / 2 + (r * 4 + ks) * 512);
        #pragma unroll
        for (int ct = 0; ct < 4; ++ct)
          a[r][ct] = __builtin_amdgcn_mfma_f32_16x16x32_bf16(u.v, BFin[ks][ct], a[r][ct], 0, 0, 0);
      }
    __builtin_amdgcn_s_setprio(0);
  };

  v8s BF1[4][4], BF2t[4][4], BF2p[4][4];
  v4f a2[4][4];

  __syncthreads();                               // bar0: c0..c3 + biases ready
  layer1(0, 0, BF1);                             // ph0 (b0=W1t)
  bias4(128, 0, a2); halfmm(16384, BF1, a2);     // ph1 (b1=W2t.lo)
  __syncthreads();                               // B1 (all reads of b0,b1 done)
  stage(32768, 0); stage(40960, 16384);          // c4 W2p.lo->b0, c5 W2p.hi->b1
  pack4(a2, BF2t, 0);                            // sunk: overlaps ph2 ds_reads
  bias4(128, 4, a2); halfmm(32768, BF1, a2);     // ph2 (b2=W2t.hi)
  layer1(49152, 256, BF1);                       // ph3 (b3=W1p)
  __syncthreads();                               // B2 (drains c4,c5)
  stage(49152, 32768); stage(65536, 49152);      // c6 W3t.lo->b2, c7 W3n.lo->b3
  pack4(a2, BF2t, 2);                            // sunk
  bias4(384, 0, a2); halfmm(0, BF1, a2);         // ph4 (b0=W2p.lo)
  pack4(a2, BF2p, 0);                            // inline (a2 reused next)
  bias4(384, 4, a2); halfmm(16384, BF1, a2);     // ph5 (b1=W2p.hi)
  __syncthreads();                               // B3 (drains c6,c7)
  stage(57344, 0); stage(73728, 16384);          // c8 W3t.hi->b0, c9 W3n.hi->b1
  pack4(a2, BF2p, 2);                            // sunk

  // ---- layer 3, rows 0..63 (lo) then 64..127 (hi); reduce each then free ----
  float p[4] = {0.f, 0.f, 0.f, 0.f};
  {
    v4f a[4][4];
    #pragma unroll
    for (int r = 0; r < 4; ++r) {
      v4f c = *(const v4f*)(Bl + 512 + r * 16 + q * 4);
      #pragma unroll
      for (int ct = 0; ct < 4; ++ct) a[r][ct] = c;
    }
    halfmm(32768, BF2t, a);                      // ph6 (b2=W3t.lo)
    halfmm(49152, BF2p, a);                      // ph7 (b3=W3n.lo)
    #pragma unroll
    for (int r = 0; r < 4; ++r)
      #pragma unroll
      for (int ct = 0; ct < 4; ++ct) {
        v4f v = a[r][ct];
        p[ct] += v[0]*v[0] + v[1]*v[1] + v[2]*v[2] + v[3]*v[3];
      }
  }
  __syncthreads();                               // B4 (drains c8,c9)
  {
    v4f a[4][4];
    #pragma unroll
    for (int r = 0; r < 4; ++r) {
      v4f c = *(const v4f*)(Bl + 512 + (r + 4) * 16 + q * 4);
      #pragma unroll
      for (int ct = 0; ct < 4; ++ct) a[r][ct] = c;
    }
    halfmm(0, BF2t, a);                          // ph8 (b0=W3t.hi)
    halfmm(16384, BF2p, a);                      // ph9 (b1=W3n.hi)
    #pragma unroll
    for (int r = 0; r < 4; ++r)
      #pragma unroll
      for (int ct = 0; ct < 4; ++ct) {
        v4f v = a[r][ct];
        p[ct] += v[0]*v[0] + v[1]*v[1] + v[2]*v[2] + v[3]*v[3];
      }
  }

  // ---- epilogue: reward = mean over 128 out-dims of diff^2 ----
  float r[4];
  #pragma unroll
  for (int ct = 0; ct < 4; ++ct) {
    p[ct] += __shfl_xor(p[ct], 32);
    p[ct] += __shfl_xor(p[ct], 16);
    r[ct] = p[ct] * (1.0f / 128.0f);
  }
  if (q == 0) {
    #pragma unroll
    for (int ct = 0; ct < 4; ++ct) rewards[s0 + ct * 16 + n] = r[ct];
  }
  float s  = r[0] + r[1] + r[2] + r[3];
  float ss = r[0]*r[0] + r[1]*r[1] + r[2]*r[2] + r[3]*r[3];
  s  += __shfl_xor(s, 8);  s  += __shfl_xor(s, 4);  s  += __shfl_xor(s, 2);  s  += __shfl_xor(s, 1);
  ss += __shfl_xor(ss, 8); ss += __shfl_xor(ss, 4); ss += __shfl_xor(ss, 2); ss += __shfl_xor(ss, 1);
  __syncthreads();                  // all reads of Wl ring done; reuse as scratch
  float* red = (float*)Wl;
  if (lane == 0) { red[wv] = s; red[8 + wv] = ss; }
  __syncthreads();
  if (t == 0) {
    atomicAdd(&sums[0], red[0] + red[1] + red[2] + red[3]);
    atomicAdd(&sums[1], red[8] + red[9] + red[10] + red[11]);
  }
}

// ---- normalize: Chan-merge with running stats ---- (UNCHANGED)
__global__ void rnd_norm(const float* __restrict__ rewards, const float* __restrict__ sums,
                         const float* __restrict__ rm, const float* __restrict__ rm2,
                         const float* __restrict__ rc, float* __restrict__ out) {
  float S = sums[0], SS = sums[1];
  float nb = (float)BATCH;
  float bm = S / nb;
  float bm2 = SS - nb * bm * bm;
  float cnt = rc[0];
  float newc = cnt + nb;
  float delta = bm - rm[0];
  float newmean = rm[0] + delta * nb / newc;
  float newm2 = rm2[0] + bm2 + delta * delta * cnt * nb / newc;
  float sd = (newc > 1.f) ? sqrtf(newm2 / (newc - 1.f)) : 1.f;
  float inv = 1.f / (sd + 1e-8f);
  int i = (blockIdx.x * 256 + threadIdx.x) * 4;
  float4 r = *(const float4*)(rewards + i);
  float4 o;
  o.x = (r.x - newmean) * inv; o.y = (r.y - newmean) * inv;
  o.z = (r.z - newmean) * inv; o.w = (r.w - newmean) * inv;
  *(float4*)(out + i) = o;
}

extern "C" void kernel_launch(void* const* d_in, const int* in_sizes, int n_in,
                              void* d_out, int out_size, void* d_ws, size_t ws_size,
                              hipStream_t stream) {
  const float* obs = (const float*)d_in[0];
  const float* rm  = (const float*)d_in[1];
  const float* rm2 = (const float*)d_in[2];
  const float* rc  = (const float*)d_in[3];
  const float* tW1 = (const float*)d_in[4];
  const float* tb1 = (const float*)d_in[5];
  const float* tW2 = (const float*)d_in[6];
  const float* tb2 = (const float*)d_in[7];
  const float* tW3 = (const float*)d_in[8];
  const float* tb3 = (const float*)d_in[9];
  const float* pW1 = (const float*)d_in[10];
  const float* pb1 = (const float*)d_in[11];
  const float* pW2 = (const float*)d_in[12];
  const float* pb2 = (const float*)d_in[13];
  const float* pW3 = (const float*)d_in[14];
  const float* pb3 = (const float*)d_in[15];

  float*    sums    = (float*)d_ws;
  float*    rewards = (float*)((char*)d_ws + 256);
  uint16_t* Wall    = (uint16_t*)((char*)d_ws + 256 + (size_t)BATCH * 4);

  (void)hipFuncSetAttribute((const void*)rnd_main,
                            hipFuncAttributeMaxDynamicSharedMemorySize, 68096);

  rnd_prep<<<40, 256, 0, stream>>>(tW1, tW2, tW3, pW1, pW2, pW3, Wall, sums);
  rnd_main<<<BATCH / 256, 256, 68096, stream>>>(obs, Wall, tb1, tb2, pb1, pb2,
                                                tb3, pb3, rewards, sums);
  rnd_norm<<<BATCH / 1024, 256, 0, stream>>>(rewards, sums, rm, rm2, rc, (float*)d_out);
}